// Round 1
// baseline (389.656 us; speedup 1.0000x reference)
//
#include <hip/hip_runtime.h>
#include <hip/hip_bf16.h>
#include <math.h>

// GanDTI forward. B=4096, N_ATOMS=50, FEAT=40, GNN_DEPTH=3, MLP_DEPTH=2.
// Kernel 1 (heterogeneous blocks):
//   blocks [0,256):    A69 [B,1001,30] single-pass stream -> a256 [B,256] (fused @W1,@W2)
//   blocks [256,4352): per-sample GNN in LDS -> compound_vec [B,40]
// Kernel 2: protein tail (p256, p40), tanh attention, 2-layer MLP, out [B,1].

#define BATCH 4096
#define NA 50
#define FEAT 40

__global__ __launch_bounds__(256) void k_heavy(
    const int* __restrict__ atoms, const float* __restrict__ A,
    const float* __restrict__ A69, const float* __restrict__ emb,
    const float* __restrict__ Wg, const float* __restrict__ bg,
    const float* __restrict__ W1, const float* __restrict__ b1,
    const float* __restrict__ W2, const float* __restrict__ b2,
    float* __restrict__ ws_cv, float* __restrict__ ws_a256)
{
    __shared__ float sm[12100];   // 48.4 KB, carved per role
    __shared__ float w1s[30];
    const int tid = threadIdx.x;
    const int blk = blockIdx.x;

    if (blk < 256) {
        // ---------------- A69 streaming path: 16 samples per block ----------------
        const int b0 = blk * 16;
        float* a69s = sm;                       // [16][65] chunk of a69
        if (tid < 30) w1s[tid] = W1[tid];
        const float b1v = b1[0];
        float acc[16];
        #pragma unroll
        for (int g = 0; g < 16; ++g) acc[g] = 0.f;

        for (int j0 = 0; j0 < 1001; j0 += 64) {
            const int ch = (1001 - j0 < 64) ? (1001 - j0) : 64;
            __syncthreads();                    // a69s reuse + w1s ready (first iter)
            for (int it = tid; it < 16 * ch; it += 256) {
                const int g = it / ch, jj = it - g * ch;
                const float2* r2 = (const float2*)(A69 + ((size_t)(b0 + g) * 1001 + j0 + jj) * 30);
                float s = 0.f;
                #pragma unroll
                for (int k = 0; k < 15; ++k) {
                    float2 v = r2[k];
                    s += v.x * w1s[2 * k] + v.y * w1s[2 * k + 1];
                }
                a69s[g * 65 + jj] = s + b1v;
            }
            __syncthreads();
            for (int jj = 0; jj < ch; ++jj) {
                const float w2v = W2[(size_t)(j0 + jj) * 256 + tid];
                #pragma unroll
                for (int g = 0; g < 16; ++g)
                    acc[g] += a69s[g * 65 + jj] * w2v;
            }
        }
        const float b2v = b2[tid];
        #pragma unroll
        for (int g = 0; g < 16; ++g)
            ws_a256[(size_t)(b0 + g) * 256 + tid] = acc[g] + b2v;
    } else {
        // ---------------- GNN path: one sample per block ----------------
        const int b = blk - 256;
        float* a_s   = sm;            // 2500 = A [50][50]
        float* comp  = sm + 2500;     // 2000
        float* comp2 = sm + 4500;     // 2000
        float* h_s   = sm + 6500;     // 2000
        float* res   = sm + 8500;     // 2000
        float* wg_s  = sm + 10500;    // 1600

        for (int idx = tid; idx < 2000; idx += 256) {
            const int n = idx / 40, f = idx - n * 40;
            const float v = emb[atoms[b * 50 + n] * 40 + f];
            comp[idx] = v; res[idx] = v;
        }
        for (int idx = tid; idx < 2500; idx += 256)
            a_s[idx] = A[(size_t)b * 2500 + idx];
        __syncthreads();

        float* cur = comp; float* nxt = comp2;
        for (int l = 0; l < 3; ++l) {
            for (int idx = tid; idx < 1600; idx += 256) wg_s[idx] = Wg[l * 1600 + idx];
            __syncthreads();
            // h = leaky_relu(cur @ Wg[l] + bg[l]) — 2 rows x 4 cols per thread
            if (tid < 250) {
                const int np = tid / 10, fg = tid - np * 10;
                const int n0 = np * 2, f0 = fg * 4;
                float acc0[4] = {0,0,0,0}, acc1[4] = {0,0,0,0};
                for (int j = 0; j < 40; ++j) {
                    const float c0 = cur[n0 * 40 + j];
                    const float c1 = cur[n0 * 40 + 40 + j];
                    #pragma unroll
                    for (int u = 0; u < 4; ++u) {
                        const float w = wg_s[j * 40 + f0 + u];
                        acc0[u] += c0 * w; acc1[u] += c1 * w;
                    }
                }
                #pragma unroll
                for (int u = 0; u < 4; ++u) {
                    const float bgv = bg[l * 40 + f0 + u];
                    const float s0 = acc0[u] + bgv;
                    const float s1 = acc1[u] + bgv;
                    h_s[n0 * 40 + f0 + u]        = s0 > 0.f ? s0 : 0.01f * s0;
                    h_s[(n0 + 1) * 40 + f0 + u]  = s1 > 0.f ? s1 : 0.01f * s1;
                }
            }
            __syncthreads();
            // nxt = cur + A @ h
            if (tid < 250) {
                const int np = tid / 10, fg = tid - np * 10;
                const int n0 = np * 2, f0 = fg * 4;
                float acc0[4] = {0,0,0,0}, acc1[4] = {0,0,0,0};
                for (int m = 0; m < 50; ++m) {
                    const float a0 = a_s[n0 * 50 + m];
                    const float a1 = a_s[n0 * 50 + 50 + m];
                    #pragma unroll
                    for (int u = 0; u < 4; ++u) {
                        const float hv = h_s[m * 40 + f0 + u];
                        acc0[u] += a0 * hv; acc1[u] += a1 * hv;
                    }
                }
                #pragma unroll
                for (int u = 0; u < 4; ++u) {
                    nxt[n0 * 40 + f0 + u]       = cur[n0 * 40 + f0 + u] + acc0[u];
                    nxt[(n0 + 1) * 40 + f0 + u] = cur[(n0 + 1) * 40 + f0 + u] + acc1[u];
                }
            }
            __syncthreads();
            float* t = cur; cur = nxt; nxt = t;
        }
        if (tid < 40) {
            float s = 0.f;
            for (int n = 0; n < 50; ++n) s += cur[n * 40 + tid] + res[n * 40 + tid];
            ws_cv[(size_t)b * 40 + tid] = s * (1.0f / 50.0f);
        }
    }
}

__global__ __launch_bounds__(256) void k_tail(
    const float* __restrict__ protein,
    const float* __restrict__ W3, const float* __restrict__ b3,
    const float* __restrict__ Wp, const float* __restrict__ bp,
    const float* __restrict__ Watt, const float* __restrict__ batt,
    const float* __restrict__ Wm, const float* __restrict__ bm,
    const float* __restrict__ Wo, const float* __restrict__ bo,
    const float* __restrict__ ws_cv, const float* __restrict__ ws_a256,
    float* __restrict__ out)
{
    const int G = 16, PC = 520;
    __shared__ float pc[16 * 520];    // protein staging, then pcat = [a256|p256]
    __shared__ float p40s[16 * 40];
    __shared__ float phs[16 * 40];
    __shared__ float wts[16];
    __shared__ float cps[2][16 * 84];
    const int tid = threadIdx.x;
    const int b0 = blockIdx.x * G;

    for (int it = tid; it < G * 512; it += 256) {
        const int g = it >> 9, j = it & 511;
        pc[g * PC + j] = protein[(size_t)(b0 + g) * 512 + j];
    }
    __syncthreads();
    // p256 = protein @ W3 + b3 : thread owns output column tid for all 16 samples
    float acc[16];
    #pragma unroll
    for (int g = 0; g < G; ++g) acc[g] = 0.f;
    for (int j = 0; j < 512; ++j) {
        const float w3 = W3[(size_t)j * 256 + tid];
        #pragma unroll
        for (int g = 0; g < G; ++g) acc[g] += pc[g * PC + j] * w3;
    }
    const float b3v = b3[tid];
    __syncthreads();
    // overwrite with pcat = [a256 | p256]
    for (int g = 0; g < G; ++g) {
        pc[g * PC + 256 + tid] = acc[g] + b3v;
        pc[g * PC + tid] = ws_a256[(size_t)(b0 + g) * 256 + tid];
    }
    __syncthreads();
    // p40 = pcat @ Wp + bp
    for (int it = tid; it < G * 40; it += 256) {
        const int g = it / 40, f = it - g * 40;
        float s = bp[f];
        for (int j = 0; j < 512; ++j)
            s += pc[g * PC + j] * Wp[j * 40 + f];
        p40s[it] = s;
    }
    __syncthreads();
    // protein_h = relu(p40 @ Watt + batt)
    for (int it = tid; it < G * 40; it += 256) {
        const int g = it / 40, f = it - g * 40;
        float s = batt[f];
        for (int j = 0; j < 40; ++j)
            s += p40s[g * 40 + j] * Watt[j * 40 + f];
        phs[it] = s > 0.f ? s : 0.f;
    }
    __syncthreads();
    if (tid < G) {
        float m = 0.f;
        for (int f = 0; f < 40; ++f)
            m += ws_cv[(size_t)(b0 + tid) * 40 + f] * phs[tid * 40 + f];
        wts[tid] = tanhf(m);
    }
    __syncthreads();
    // cp = [compound_vec | weights * protein_h]
    for (int it = tid; it < G * 80; it += 256) {
        const int g = it / 80, f = it - g * 80;
        const float v = (f < 40) ? ws_cv[(size_t)(b0 + g) * 40 + f]
                                 : wts[g] * phs[g * 40 + (f - 40)];
        cps[0][g * 84 + f] = v;
    }
    __syncthreads();
    int cb = 0;
    for (int l = 0; l < 2; ++l) {
        for (int it = tid; it < G * 80; it += 256) {
            const int g = it / 80, k = it - g * 80;
            float s = bm[l * 80 + k];
            for (int j = 0; j < 80; ++j)
                s += cps[cb][g * 84 + j] * Wm[l * 6400 + j * 80 + k];
            cps[cb ^ 1][g * 84 + k] = s > 0.f ? s : 0.f;
        }
        __syncthreads();
        cb ^= 1;
    }
    if (tid < G) {
        float s = bo[0];
        for (int j = 0; j < 80; ++j)
            s += cps[cb][tid * 84 + j] * Wo[j];
        out[b0 + tid] = s;
    }
}

extern "C" void kernel_launch(void* const* d_in, const int* in_sizes, int n_in,
                              void* d_out, int out_size, void* d_ws, size_t ws_size,
                              hipStream_t stream) {
    const int*   atoms   = (const int*)d_in[0];
    const float* A       = (const float*)d_in[1];
    const float* A69     = (const float*)d_in[2];
    const float* protein = (const float*)d_in[3];
    const float* emb     = (const float*)d_in[4];
    const float* Wg      = (const float*)d_in[5];
    const float* bg      = (const float*)d_in[6];
    const float* Watt    = (const float*)d_in[7];
    const float* batt    = (const float*)d_in[8];
    const float* W1      = (const float*)d_in[9];
    const float* b1      = (const float*)d_in[10];
    const float* W2      = (const float*)d_in[11];
    const float* b2      = (const float*)d_in[12];
    const float* W3      = (const float*)d_in[13];
    const float* b3      = (const float*)d_in[14];
    const float* Wp      = (const float*)d_in[15];
    const float* bp      = (const float*)d_in[16];
    const float* Wm      = (const float*)d_in[17];
    const float* bm      = (const float*)d_in[18];
    const float* Wo      = (const float*)d_in[19];
    const float* bo      = (const float*)d_in[20];

    float* ws_cv   = (float*)d_ws;                 // [4096][40]
    float* ws_a256 = ws_cv + (size_t)BATCH * FEAT; // [4096][256]
    float* out     = (float*)d_out;

    k_heavy<<<dim3(BATCH + 256), dim3(256), 0, stream>>>(
        atoms, A, A69, emb, Wg, bg, W1, b1, W2, b2, ws_cv, ws_a256);
    k_tail<<<dim3(256), dim3(256), 0, stream>>>(
        protein, W3, b3, Wp, bp, Watt, batt, Wm, bm, Wo, bo, ws_cv, ws_a256, out);
}

// Round 2
// 371.858 us; speedup vs baseline: 1.0479x; 1.0479x over previous
//
#include <hip/hip_runtime.h>
#include <hip/hip_bf16.h>
#include <math.h>

// GanDTI forward. B=4096, N_ATOMS=50, FEAT=40, GNN_DEPTH=3, MLP_DEPTH=2.
// k_heavy (heterogeneous blocks):
//   blocks [0,512):    A69 [B,1001,30] single-pass stream -> a256 [B,256]
//                      (fused @W1,@W2), 8 samples/block, ping-pong LDS chunks
//   blocks [512,4608): per-sample GNN in LDS (b128 everywhere, padded strides,
//                      in-place comp update, residual folded into init column-sum)
// k_tail: protein tail (p256, p40), tanh attention, 2-layer MLP -> out [B,1].

#define BATCH 4096

// LDS layout (floats), GNN path: a_s [50][52] @0, comp [50][44] @2600,
// h [50][44] @4800, wg [40][40] @7000  -> 8600 floats = 34.4 KB -> 4 blocks/CU.
#define SA 52
#define SC 44

__global__ __launch_bounds__(256) void k_heavy(
    const int* __restrict__ atoms, const float* __restrict__ A,
    const float* __restrict__ A69, const float* __restrict__ emb,
    const float* __restrict__ Wg, const float* __restrict__ bg,
    const float* __restrict__ W1, const float* __restrict__ b1,
    const float* __restrict__ W2, const float* __restrict__ b2,
    float* __restrict__ ws_cv, float* __restrict__ ws_a256)
{
    __shared__ float sm[8600];
    const int tid = threadIdx.x;
    const int blk = blockIdx.x;

    if (blk < 512) {
        // ---------------- A69 streaming: 8 samples/block, ping-pong ----------------
        const int b0 = blk * 8;
        float* buf0 = sm;          // [8][65]
        float* buf1 = sm + 520;

        float w1r[30];
        #pragma unroll
        for (int k = 0; k < 30; ++k) w1r[k] = W1[k];
        const float b1v = b1[0];

        const int g1 = tid >> 6, jj1 = tid & 63;   // row tid
        const int g2 = g1 + 4;                     // row tid+256

        float acc[8];
        #pragma unroll
        for (int g = 0; g < 8; ++g) acc[g] = 0.f;

        // prologue: chunk 0 (jc=64, all valid)
        {
            const float2* p1 = (const float2*)(A69 + ((size_t)(b0 + g1) * 1001 + jj1) * 30);
            const float2* p2 = (const float2*)(A69 + ((size_t)(b0 + g2) * 1001 + jj1) * 30);
            float s1 = b1v, s2 = b1v;
            #pragma unroll
            for (int k = 0; k < 15; ++k) {
                float2 t1 = p1[k], t2 = p2[k];
                s1 = fmaf(t1.x, w1r[2 * k], s1); s1 = fmaf(t1.y, w1r[2 * k + 1], s1);
                s2 = fmaf(t2.x, w1r[2 * k], s2); s2 = fmaf(t2.y, w1r[2 * k + 1], s2);
            }
            buf0[g1 * 65 + jj1] = s1;
            buf0[g2 * 65 + jj1] = s2;
        }
        __syncthreads();

        float* cur = buf0; float* nxt = buf1;
        for (int c = 0; c < 16; ++c) {
            // prefetch+dot chunk c+1 into registers
            float s1 = 0.f, s2 = 0.f; bool v = false;
            if (c < 15) {
                const int j0n = (c + 1) * 64;
                const int jcn = (1001 - j0n < 64) ? (1001 - j0n) : 64;
                v = (jj1 < jcn);
                if (v) {
                    const float2* p1 = (const float2*)(A69 + ((size_t)(b0 + g1) * 1001 + j0n + jj1) * 30);
                    const float2* p2 = (const float2*)(A69 + ((size_t)(b0 + g2) * 1001 + j0n + jj1) * 30);
                    s1 = b1v; s2 = b1v;
                    #pragma unroll
                    for (int k = 0; k < 15; ++k) {
                        float2 t1 = p1[k], t2 = p2[k];
                        s1 = fmaf(t1.x, w1r[2 * k], s1); s1 = fmaf(t1.y, w1r[2 * k + 1], s1);
                        s2 = fmaf(t2.x, w1r[2 * k], s2); s2 = fmaf(t2.y, w1r[2 * k + 1], s2);
                    }
                }
            }
            // accumulate chunk c
            const int j0 = c * 64;
            const int jc = (1001 - j0 < 64) ? (1001 - j0) : 64;
            const float* w2p = W2 + (size_t)j0 * 256 + tid;
            if (jc == 64) {
                #pragma unroll 8
                for (int jj = 0; jj < 64; ++jj) {
                    const float w2v = w2p[(size_t)jj * 256];
                    #pragma unroll
                    for (int g = 0; g < 8; ++g) acc[g] = fmaf(cur[g * 65 + jj], w2v, acc[g]);
                }
            } else {
                for (int jj = 0; jj < jc; ++jj) {
                    const float w2v = w2p[(size_t)jj * 256];
                    #pragma unroll
                    for (int g = 0; g < 8; ++g) acc[g] = fmaf(cur[g * 65 + jj], w2v, acc[g]);
                }
            }
            __syncthreads();
            if (v) { nxt[g1 * 65 + jj1] = s1; nxt[g2 * 65 + jj1] = s2; }
            __syncthreads();
            float* t = cur; cur = nxt; nxt = t;
        }
        const float b2v = b2[tid];
        #pragma unroll
        for (int g = 0; g < 8; ++g)
            ws_a256[(size_t)(b0 + g) * 256 + tid] = acc[g] + b2v;
    } else {
        // ---------------- GNN: one sample per block ----------------
        const int b = blk - 512;
        float* a_s  = sm;          // [50][SA]
        float* comp = sm + 2600;   // [50][SC]
        float* h_s  = sm + 4800;   // [50][SC]
        float* wg_s = sm + 7000;   // [40][40]

        // stage A (padded stride SA)
        for (int idx = tid; idx < 2500; idx += 256) {
            const int n = idx / 50, m = idx - n * 50;
            a_s[n * SA + m] = A[(size_t)b * 2500 + idx];
        }
        // stage emb -> comp (float4 per (n, f-quad))
        for (int idx = tid; idx < 500; idx += 256) {
            const int n = idx / 10, f4 = idx - n * 10;
            const int row = atoms[b * 50 + n];
            *(float4*)(comp + n * SC + f4 * 4) = *(const float4*)(emb + row * 40 + f4 * 4);
        }
        // stage Wg layer 0
        if (tid < 256) *(float4*)(wg_s + tid * 4) = *(const float4*)(Wg + tid * 4);
        if (tid < 144) *(float4*)(wg_s + 1024 + tid * 4) = *(const float4*)(Wg + 1024 + tid * 4);
        __syncthreads();

        // residual column sum (kept in register, lanes 0..39)
        float res_sum = 0.f;
        if (tid < 40) {
            for (int n = 0; n < 50; ++n) res_sum += comp[n * SC + tid];
        }

        const int np = tid / 10, fg = tid - np * 10;
        const int n0 = np * 2, f0 = fg * 4;
        const bool act = (tid < 250);

        for (int l = 0; l < 3; ++l) {
            // prefetch next layer's Wg into registers (written after h-barrier)
            float4 wgp0, wgp1;
            if (l < 2) {
                wgp0 = *(const float4*)(Wg + (l + 1) * 1600 + tid * 4);
                if (tid < 144) wgp1 = *(const float4*)(Wg + (l + 1) * 1600 + 1024 + tid * 4);
            }
            // matmul1: h = leaky_relu(comp @ Wg[l] + bg[l]), 2 rows x 4 cols / thread
            if (act) {
                float4 bgv = *(const float4*)(bg + l * 40 + f0);
                float acc0[4] = {bgv.x, bgv.y, bgv.z, bgv.w};
                float acc1[4] = {bgv.x, bgv.y, bgv.z, bgv.w};
                #pragma unroll
                for (int j4 = 0; j4 < 40; j4 += 4) {
                    float c0a[4], c1a[4];
                    *(float4*)c0a = *(float4*)(comp + n0 * SC + j4);
                    *(float4*)c1a = *(float4*)(comp + n0 * SC + SC + j4);
                    #pragma unroll
                    for (int u = 0; u < 4; ++u) {
                        float wv[4];
                        *(float4*)wv = *(float4*)(wg_s + (j4 + u) * 40 + f0);
                        #pragma unroll
                        for (int q = 0; q < 4; ++q) {
                            acc0[q] = fmaf(c0a[u], wv[q], acc0[q]);
                            acc1[q] = fmaf(c1a[u], wv[q], acc1[q]);
                        }
                    }
                }
                float h0[4], h1[4];
                #pragma unroll
                for (int q = 0; q < 4; ++q) {
                    h0[q] = acc0[q] > 0.f ? acc0[q] : 0.01f * acc0[q];
                    h1[q] = acc1[q] > 0.f ? acc1[q] : 0.01f * acc1[q];
                }
                *(float4*)(h_s + n0 * SC + f0) = *(float4*)h0;
                *(float4*)(h_s + n0 * SC + SC + f0) = *(float4*)h1;
            }
            __syncthreads();
            // write prefetched Wg (matmul2 below does not read wg_s)
            if (l < 2) {
                *(float4*)(wg_s + tid * 4) = wgp0;
                if (tid < 144) *(float4*)(wg_s + 1024 + tid * 4) = wgp1;
            }
            // matmul2: comp += A @ h (in-place, thread-owned cells)
            if (act) {
                float acc0[4] = {0, 0, 0, 0}, acc1[4] = {0, 0, 0, 0};
                #pragma unroll
                for (int m4 = 0; m4 < 48; m4 += 4) {
                    float a0a[4], a1a[4];
                    *(float4*)a0a = *(float4*)(a_s + n0 * SA + m4);
                    *(float4*)a1a = *(float4*)(a_s + n0 * SA + SA + m4);
                    #pragma unroll
                    for (int u = 0; u < 4; ++u) {
                        float hv[4];
                        *(float4*)hv = *(float4*)(h_s + (m4 + u) * SC + f0);
                        #pragma unroll
                        for (int q = 0; q < 4; ++q) {
                            acc0[q] = fmaf(a0a[u], hv[q], acc0[q]);
                            acc1[q] = fmaf(a1a[u], hv[q], acc1[q]);
                        }
                    }
                }
                #pragma unroll
                for (int m = 48; m < 50; ++m) {
                    const float a0 = a_s[n0 * SA + m], a1 = a_s[n0 * SA + SA + m];
                    float hv[4];
                    *(float4*)hv = *(float4*)(h_s + m * SC + f0);
                    #pragma unroll
                    for (int q = 0; q < 4; ++q) {
                        acc0[q] = fmaf(a0, hv[q], acc0[q]);
                        acc1[q] = fmaf(a1, hv[q], acc1[q]);
                    }
                }
                float c0a[4], c1a[4];
                *(float4*)c0a = *(float4*)(comp + n0 * SC + f0);
                *(float4*)c1a = *(float4*)(comp + n0 * SC + SC + f0);
                #pragma unroll
                for (int q = 0; q < 4; ++q) { c0a[q] += acc0[q]; c1a[q] += acc1[q]; }
                *(float4*)(comp + n0 * SC + f0) = *(float4*)c0a;
                *(float4*)(comp + n0 * SC + SC + f0) = *(float4*)c1a;
            }
            __syncthreads();
        }
        // mean over atoms + residual
        if (tid < 40) {
            float s = res_sum;
            for (int n = 0; n < 50; ++n) s += comp[n * SC + tid];
            ws_cv[(size_t)b * 40 + tid] = s * 0.02f;
        }
    }
}

__global__ __launch_bounds__(256) void k_tail(
    const float* __restrict__ protein,
    const float* __restrict__ W3, const float* __restrict__ b3,
    const float* __restrict__ Wp, const float* __restrict__ bp,
    const float* __restrict__ Watt, const float* __restrict__ batt,
    const float* __restrict__ Wm, const float* __restrict__ bm,
    const float* __restrict__ Wo, const float* __restrict__ bo,
    const float* __restrict__ ws_cv, const float* __restrict__ ws_a256,
    float* __restrict__ out)
{
    const int G = 8, PC = 520;
    __shared__ float pc[8 * 520];
    __shared__ float p40s[8 * 40];
    __shared__ float phs[8 * 40];
    __shared__ float wts[8];
    __shared__ float cps[2][8 * 84];
    const int tid = threadIdx.x;
    const int b0 = blockIdx.x * G;

    // stage protein (float4)
    #pragma unroll
    for (int r = 0; r < 4; ++r) {
        const int it = tid + r * 256;          // over 8*128 float4 units
        const int g = it >> 7, u = it & 127;
        *(float4*)(pc + g * PC + u * 4) = *(const float4*)(protein + (size_t)(b0 + g) * 512 + u * 4);
    }
    __syncthreads();
    // p256 = protein @ W3 + b3 (thread owns col tid for all 8 samples)
    float acc[8];
    #pragma unroll
    for (int g = 0; g < G; ++g) acc[g] = 0.f;
    #pragma unroll 4
    for (int j = 0; j < 512; ++j) {
        const float w3 = W3[(size_t)j * 256 + tid];
        #pragma unroll
        for (int g = 0; g < G; ++g) acc[g] = fmaf(pc[g * PC + j], w3, acc[g]);
    }
    const float b3v = b3[tid];
    __syncthreads();
    // pcat = [a256 | p256]
    for (int g = 0; g < G; ++g) {
        pc[g * PC + 256 + tid] = acc[g] + b3v;
        pc[g * PC + tid] = ws_a256[(size_t)(b0 + g) * 256 + tid];
    }
    __syncthreads();
    // p40 = pcat @ Wp + bp
    if (tid < 160) {} // (keep all threads for loop below)
    for (int it = tid; it < G * 40; it += 256) {
        const int g = it / 40, f = it - g * 40;
        float s = bp[f];
        #pragma unroll 4
        for (int j = 0; j < 512; ++j)
            s = fmaf(pc[g * PC + j], Wp[j * 40 + f], s);
        p40s[it] = s;
    }
    __syncthreads();
    // protein_h = relu(p40 @ Watt + batt)
    for (int it = tid; it < G * 40; it += 256) {
        const int g = it / 40, f = it - g * 40;
        float s = batt[f];
        #pragma unroll
        for (int j = 0; j < 40; ++j)
            s = fmaf(p40s[g * 40 + j], Watt[j * 40 + f], s);
        phs[it] = s > 0.f ? s : 0.f;
    }
    __syncthreads();
    if (tid < G) {
        float m = 0.f;
        for (int f = 0; f < 40; ++f)
            m += ws_cv[(size_t)(b0 + tid) * 40 + f] * phs[tid * 40 + f];
        wts[tid] = tanhf(m);
    }
    __syncthreads();
    // cp = [compound_vec | weights * protein_h]
    for (int it = tid; it < G * 80; it += 256) {
        const int g = it / 80, f = it - g * 80;
        const float v = (f < 40) ? ws_cv[(size_t)(b0 + g) * 40 + f]
                                 : wts[g] * phs[g * 40 + (f - 40)];
        cps[0][g * 84 + f] = v;
    }
    __syncthreads();
    int cb = 0;
    for (int l = 0; l < 2; ++l) {
        for (int it = tid; it < G * 80; it += 256) {
            const int g = it / 80, k = it - g * 80;
            float s = bm[l * 80 + k];
            #pragma unroll 4
            for (int j = 0; j < 80; ++j)
                s = fmaf(cps[cb][g * 84 + j], Wm[l * 6400 + j * 80 + k], s);
            cps[cb ^ 1][g * 84 + k] = s > 0.f ? s : 0.f;
        }
        __syncthreads();
        cb ^= 1;
    }
    if (tid < G) {
        float s = bo[0];
        for (int j = 0; j < 80; ++j)
            s = fmaf(cps[cb][tid * 84 + j], Wo[j], s);
        out[b0 + tid] = s;
    }
}

extern "C" void kernel_launch(void* const* d_in, const int* in_sizes, int n_in,
                              void* d_out, int out_size, void* d_ws, size_t ws_size,
                              hipStream_t stream) {
    const int*   atoms   = (const int*)d_in[0];
    const float* A       = (const float*)d_in[1];
    const float* A69     = (const float*)d_in[2];
    const float* protein = (const float*)d_in[3];
    const float* emb     = (const float*)d_in[4];
    const float* Wg      = (const float*)d_in[5];
    const float* bg      = (const float*)d_in[6];
    const float* Watt    = (const float*)d_in[7];
    const float* batt    = (const float*)d_in[8];
    const float* W1      = (const float*)d_in[9];
    const float* b1      = (const float*)d_in[10];
    const float* W2      = (const float*)d_in[11];
    const float* b2      = (const float*)d_in[12];
    const float* W3      = (const float*)d_in[13];
    const float* b3      = (const float*)d_in[14];
    const float* Wp      = (const float*)d_in[15];
    const float* bp      = (const float*)d_in[16];
    const float* Wm      = (const float*)d_in[17];
    const float* bm      = (const float*)d_in[18];
    const float* Wo      = (const float*)d_in[19];
    const float* bo      = (const float*)d_in[20];

    float* ws_cv   = (float*)d_ws;                  // [4096][40]
    float* ws_a256 = ws_cv + (size_t)BATCH * 40;    // [4096][256]
    float* out     = (float*)d_out;

    k_heavy<<<dim3(512 + BATCH), dim3(256), 0, stream>>>(
        atoms, A, A69, emb, Wg, bg, W1, b1, W2, b2, ws_cv, ws_a256);
    k_tail<<<dim3(512), dim3(256), 0, stream>>>(
        protein, W3, b3, Wp, bp, Watt, batt, Wm, bm, Wo, bo, ws_cv, ws_a256, out);
}